// Round 7
// baseline (388.256 us; speedup 1.0000x reference)
//
#include <hip/hip_runtime.h>
#include <cstddef>
#include <cstdint>
#include <type_traits>

#define N_NODES 20000
#define NPAD 20096            // multiple of 128 for MFMA row tiles
#define E0_EDGES 160000
#define E_TOT (E0_EDGES + N_NODES)
#define CAP 64                // max in-degree slots (Poisson(9); P(>=64) ~ 0)

typedef __bf16 bf16x8 __attribute__((ext_vector_type(8)));
typedef float f32x4 __attribute__((ext_vector_type(4)));

__device__ __forceinline__ ushort f2bf(float f) {
  uint32_t u = __float_as_uint(f);
  return (ushort)((u + 0x7FFFu + ((u >> 16) & 1u)) >> 16);  // RNE
}
__device__ __forceinline__ float bf2f(ushort h) {
  return __uint_as_float((uint32_t)h << 16);
}

// ======================= CSR via fixed-stride slots ==========================

__global__ void fill_csr_kernel(const int* __restrict__ ei, int* __restrict__ cnt,
                                int* __restrict__ slots) {
  int e = blockIdx.x * blockDim.x + threadIdx.x;
  if (e >= E_TOT) return;
  int src, dst;
  if (e < E0_EDGES) { src = ei[e]; dst = ei[E0_EDGES + e]; }
  else              { src = e - E0_EDGES; dst = src; }
  int pos = atomicAdd(&cnt[dst], 1);
  if (pos < CAP) slots[dst * CAP + pos] = src;
}

// ======================= fp32 -> bf16 conversion =============================

__global__ void convert_x_kernel(const float* __restrict__ x, ushort* __restrict__ xb) {
  size_t i = ((size_t)blockIdx.x * blockDim.x + threadIdx.x) * 4;
  if (i >= (size_t)NPAD * 512) return;
  if (i < (size_t)N_NODES * 512) {
    float4 v = *(const float4*)(x + i);
    ushort4 o;
    o.x = f2bf(v.x); o.y = f2bf(v.y); o.z = f2bf(v.z); o.w = f2bf(v.w);
    *(ushort4*)(xb + i) = o;
  } else {
    *(ushort4*)(xb + i) = make_ushort4(0, 0, 0, 0);
  }
}

// Bt[m][k] = bf16(W[k][m]); all six weight matrices in one launch (z selects)
__global__ void transpose_all_kernel(
    const float* __restrict__ W1, const float* __restrict__ lW1,
    const float* __restrict__ W2, const float* __restrict__ lW2,
    const float* __restrict__ W3, const float* __restrict__ lW3,
    ushort* __restrict__ Bt1, ushort* __restrict__ Bt2, ushort* __restrict__ Bt3) {
  __shared__ float tile[32][33];
  const int K = 512;
  int z = blockIdx.z;
  const float* W; ushort* B; int M;
  switch (z) {
    case 0:  W = W1;  B = Bt1;              M = 512; break;
    case 1:  W = lW1; B = Bt1 + 512 * 512;  M = 512; break;
    case 2:  W = W2;  B = Bt2;              M = 512; break;
    case 3:  W = lW2; B = Bt2 + 512 * 512;  M = 512; break;
    case 4:  W = W3;  B = Bt3;              M = 384; break;
    default: W = lW3; B = Bt3 + 384 * 512;  M = 64;  break;
  }
  int mb = blockIdx.x * 32, kb = blockIdx.y * 32;
  if (mb >= M) return;
  int tx = threadIdx.x, ty = threadIdx.y;  // 32 x 8
#pragma unroll
  for (int i = 0; i < 32; i += 8)
    tile[ty + i][tx] = W[(size_t)(kb + ty + i) * M + mb + tx];
  __syncthreads();
#pragma unroll
  for (int i = 0; i < 32; i += 8)
    B[(size_t)(mb + ty + i) * K + kb + tx] = f2bf(tile[tx][ty + i]);
}

// ======================= bf16 MFMA GEMM — register-only, barrier-free ========
// C[nrow x Ncols] = A @ Bt^T; cols<split -> out0 (bf16) + fused att scores;
// cols>=split -> out1 (+bias1). 128x128 block tile, 4 waves, NO LDS, NO syncs.
// A/B fragments are loaded global->VGPR each K-step (L2/L3-resident panels);
// fully unrolled K=512 loop, compile-time load offsets.

template <typename Out1T>
__global__ __launch_bounds__(256) void mfma_gemm_kernel(
    const ushort* __restrict__ A,   // [NPAD][512] bf16
    const ushort* __restrict__ Bt,  // [colpad][512] bf16
    ushort* __restrict__ out0, int ld0, int split,
    Out1T* __restrict__ out1, int ld1, int Mout1, const float* __restrict__ bias1,
    const float* __restrict__ att_sw, const float* __restrict__ att_dw,  // [H][C]
    float* __restrict__ a_sp, float* __restrict__ a_dp,  // [N*H*2] half-parts
    int nheads, int headC,
    int nBy, int nwg) {
  const int K = 512;

  // bijective XCD-chunked swizzle (m204); column-tile-major linearization so
  // each XCD keeps one B panel (1 MB) L2-hot while streaming A.
  int q = nwg >> 3, r = nwg & 7;
  int orig = blockIdx.x;
  int xcd = orig & 7, pos = orig >> 3;
  int wgid = (xcd < r ? xcd * (q + 1) : r * (q + 1) + (xcd - r) * q) + pos;
  int bx = wgid / nBy, by = wgid - bx * nBy;   // col-major: consecutive = same bx
  int bm = by * 128, bn = bx * 128;

  int tid = threadIdx.x, lane = tid & 63, wave = tid >> 6;
  int wrow = (wave >> 1) * 64, wcol = (wave & 1) * 64;
  int fr = lane & 15, hi = lane >> 4;

  // per-lane fragment base pointers (advance by k*64 bytes, folded as imm)
  const char* pa[4];
  const char* pb[4];
#pragma unroll
  for (int i = 0; i < 4; ++i)
    pa[i] = (const char*)(A + (size_t)(bm + wrow + i * 16 + fr) * K + hi * 8);
#pragma unroll
  for (int j = 0; j < 4; ++j)
    pb[j] = (const char*)(Bt + (size_t)(bn + wcol + j * 16 + fr) * K + hi * 8);

  f32x4 acc[4][4] = {};

#pragma unroll
  for (int k = 0; k < 16; ++k) {
    bf16x8 af[4], bf[4];
#pragma unroll
    for (int i = 0; i < 4; ++i) af[i] = *(const bf16x8*)(pa[i] + k * 64);
#pragma unroll
    for (int j = 0; j < 4; ++j) bf[j] = *(const bf16x8*)(pb[j] + k * 64);
#pragma unroll
    for (int i = 0; i < 4; ++i)
#pragma unroll
      for (int j = 0; j < 4; ++j)
        acc[i][j] = __builtin_amdgcn_mfma_f32_16x16x32_bf16(af[i], bf[j], acc[i][j], 0, 0, 0);
  }

  // ---- epilogue: C/D layout col=lane&15, row=(lane>>4)*4+reg [m89/m91] ----
  int colg = bn + wcol;            // 64-aligned, wave-uniform
  bool lower = colg < split;
  int g4 = hi << 2;
  int ccol = fr;
#pragma unroll
  for (int i = 0; i < 4; ++i) {
#pragma unroll
    for (int rr = 0; rr < 4; ++rr) {
      int row = bm + wrow + g4 + i * 16 + rr;
      if (row >= N_NODES) continue;
#pragma unroll
      for (int j = 0; j < 4; ++j) {
        int col = colg + j * 16 + ccol;
        float v = acc[i][j][rr];
        if (lower) {
          out0[(size_t)row * ld0 + col] = f2bf(v);
        } else {
          int c1 = col - split;
          if (c1 < Mout1) {
            float b = v + bias1[c1];
            if constexpr (std::is_same<Out1T, ushort>::value)
              out1[(size_t)row * ld1 + c1] = f2bf(b);
            else
              out1[(size_t)row * ld1 + c1] = b;
          }
        }
      }
    }
  }

  // ---- fused attention scores: a_s/a_d = h . att over this wave's 64 cols ----
  // headC==128: wave covers half a head -> write part[half]; headC==64: whole
  // head -> write part[0], zero part[1]. Every slot written exactly once.
  if (lower) {
    int hd = colg / headC;               // wave-uniform head
    int cb = colg - hd * headC;          // 0 or 64
    int half = (cb >> 6) & 1;
    float ws4[4], wd4[4];
#pragma unroll
    for (int j = 0; j < 4; ++j) {
      int cc = hd * headC + cb + j * 16 + ccol;
      ws4[j] = att_sw[cc];
      wd4[j] = att_dw[cc];
    }
#pragma unroll
    for (int i = 0; i < 4; ++i) {
#pragma unroll
      for (int rr = 0; rr < 4; ++rr) {
        float ps = 0.f, pd = 0.f;
#pragma unroll
        for (int j = 0; j < 4; ++j) { ps += acc[i][j][rr] * ws4[j]; pd += acc[i][j][rr] * wd4[j]; }
#pragma unroll
        for (int o = 1; o < 16; o <<= 1) { ps += __shfl_xor(ps, o); pd += __shfl_xor(pd, o); }
        if ((lane & 15) == 0) {
          int row = bm + wrow + g4 + i * 16 + rr;
          if (row < N_NODES) {
            size_t idx = ((size_t)row * nheads + hd) * 2;
            if (headC == 128) {
              a_sp[idx + half] = ps;
              a_dp[idx + half] = pd;
            } else {
              a_sp[idx] = ps;  a_sp[idx + 1] = 0.f;
              a_dp[idx] = pd;  a_dp[idx + 1] = 0.f;
            }
          }
        }
      }
    }
  }
}

// ======================= fused softmax + gather (layers 1,2) =================
// 128 threads: 2 waves do softmax for 2 heads each; then thread t owns
// features 4t..4t+3 (head = t>>5), 8B vector loads per edge.

template <int H, int C>
__global__ __launch_bounds__(128) void gather12_fused(
    const int* __restrict__ cnt, const int* __restrict__ slots,
    const float* __restrict__ a_sp, const float* __restrict__ a_dp,
    const ushort* __restrict__ hbuf, const float* __restrict__ gat_bias,
    const ushort* __restrict__ skip_in, ushort* __restrict__ outbuf) {
  __shared__ float al[H][CAP];
  __shared__ int srcs[CAP];
  int n = blockIdx.x;
  int t = threadIdx.x, lane = t & 63, w = t >> 6;  // 2 waves
  int deg = min(cnt[n], CAP);

  int sj = 0;
  if (lane < deg) sj = slots[n * CAP + lane];
#pragma unroll
  for (int hh = 0; hh < 2; ++hh) {
    int hd = 2 * w + hh;
    float e = -1e30f;
    if (lane < deg) {
      size_t is = ((size_t)sj * H + hd) * 2;
      size_t id = ((size_t)n * H + hd) * 2;
      float v = a_sp[is] + a_sp[is + 1] + a_dp[id] + a_dp[id + 1];
      e = v > 0.f ? v : 0.2f * v;  // leaky_relu
    }
    float m = e;
#pragma unroll
    for (int o = 32; o > 0; o >>= 1) m = fmaxf(m, __shfl_xor(m, o));
    float ex = (lane < deg) ? expf(e - m) : 0.f;
    float s = ex;
#pragma unroll
    for (int o = 32; o > 0; o >>= 1) s += __shfl_xor(s, o);
    float inv = 1.f / (s + 1e-16f);
    if (lane < deg) al[hd][lane] = ex * inv;
  }
  if (w == 0 && lane < deg) srcs[lane] = sj;
  __syncthreads();

  int f0 = 4 * t, hd = t >> 5;  // features 4t..4t+3, all in head t>>5
  float a0 = 0.f, a1 = 0.f, a2 = 0.f, a3 = 0.f;
  for (int j = 0; j < deg; ++j) {
    float a = al[hd][j];
    ushort4 hv = *(const ushort4*)(hbuf + (size_t)srcs[j] * (H * C) + f0);
    a0 += a * bf2f(hv.x);
    a1 += a * bf2f(hv.y);
    a2 += a * bf2f(hv.z);
    a3 += a * bf2f(hv.w);
  }
  ushort4 sk = *(const ushort4*)(skip_in + (size_t)n * (H * C) + f0);
  float o0 = a0 + gat_bias[f0 + 0] + bf2f(sk.x);
  float o1 = a1 + gat_bias[f0 + 1] + bf2f(sk.y);
  float o2 = a2 + gat_bias[f0 + 2] + bf2f(sk.z);
  float o3 = a3 + gat_bias[f0 + 3] + bf2f(sk.w);
  o0 = o0 > 0.f ? o0 : (expf(o0) - 1.f);  // ELU
  o1 = o1 > 0.f ? o1 : (expf(o1) - 1.f);
  o2 = o2 > 0.f ? o2 : (expf(o2) - 1.f);
  o3 = o3 > 0.f ? o3 : (expf(o3) - 1.f);
  ushort4 ov;
  ov.x = f2bf(o0); ov.y = f2bf(o1); ov.z = f2bf(o2); ov.w = f2bf(o3);
  *(ushort4*)(outbuf + (size_t)n * (H * C) + f0) = ov;
}

// ======================= fused softmax + gather (layer 3, mean heads) ========

__global__ __launch_bounds__(128) void gather3_fused(
    const int* __restrict__ cnt, const int* __restrict__ slots,
    const float* __restrict__ a_sp, const float* __restrict__ a_dp,
    const ushort* __restrict__ hbuf /*N x 384*/, const float* __restrict__ b3,
    float* __restrict__ out /*N x 64, holds skip+lb3*/) {
  __shared__ float al[6][CAP];
  __shared__ int srcs[CAP];
  __shared__ float part[2][64];
  int n = blockIdx.x;
  int t = threadIdx.x, lane = t & 63, w = t >> 6;
  int deg = min(cnt[n], CAP);

  int sj = 0;
  if (lane < deg) sj = slots[n * CAP + lane];
#pragma unroll
  for (int hh = 0; hh < 3; ++hh) {
    int hd = 3 * w + hh;
    float e = -1e30f;
    if (lane < deg) {
      size_t is = ((size_t)sj * 6 + hd) * 2;
      size_t id = ((size_t)n * 6 + hd) * 2;
      float v = a_sp[is] + a_sp[is + 1] + a_dp[id] + a_dp[id + 1];
      e = v > 0.f ? v : 0.2f * v;
    }
    float m = e;
#pragma unroll
    for (int o = 32; o > 0; o >>= 1) m = fmaxf(m, __shfl_xor(m, o));
    float ex = (lane < deg) ? expf(e - m) : 0.f;
    float s = ex;
#pragma unroll
    for (int o = 32; o > 0; o >>= 1) s += __shfl_xor(s, o);
    float inv = (1.f / 6.f) / (s + 1e-16f);  // fold mean over heads
    if (lane < deg) al[hd][lane] = ex * inv;
  }
  if (w == 0 && lane < deg) srcs[lane] = sj;
  __syncthreads();

  int c = t & 63;
  float acc = 0.f;
  for (int j = w; j < deg; j += 2) {
    const ushort* hr = hbuf + (size_t)srcs[j] * 384 + c;
#pragma unroll
    for (int hd = 0; hd < 6; ++hd) acc += al[hd][j] * bf2f(hr[hd * 64]);
  }
  part[w][c] = acc;
  __syncthreads();
  if (t < 64) {
    size_t oi = (size_t)n * 64 + t;
    out[oi] += part[0][t] + part[1][t] + b3[t];
  }
}

// ======================= host launch =========================================

extern "C" void kernel_launch(void* const* d_in, const int* in_sizes, int n_in,
                              void* d_out, int out_size, void* d_ws, size_t ws_size,
                              hipStream_t stream) {
  const float* x   = (const float*)d_in[0];
  const int*   ei  = (const int*)d_in[1];
  const float* W1  = (const float*)d_in[2];
  const float* as1 = (const float*)d_in[3];
  const float* ad1 = (const float*)d_in[4];
  const float* b1  = (const float*)d_in[5];
  const float* lW1 = (const float*)d_in[6];
  const float* lb1 = (const float*)d_in[7];
  const float* W2  = (const float*)d_in[8];
  const float* as2 = (const float*)d_in[9];
  const float* ad2 = (const float*)d_in[10];
  const float* b2  = (const float*)d_in[11];
  const float* lW2 = (const float*)d_in[12];
  const float* lb2 = (const float*)d_in[13];
  const float* W3  = (const float*)d_in[14];
  const float* as3 = (const float*)d_in[15];
  const float* ad3 = (const float*)d_in[16];
  const float* b3  = (const float*)d_in[17];
  const float* lW3 = (const float*)d_in[18];
  const float* lb3 = (const float*)d_in[19];
  float* out = (float*)d_out;

  char* ws = (char*)d_ws;
  auto alloc = [&](size_t bytes) -> void* {
    void* p = (void*)ws;
    ws += (bytes + 255) & ~(size_t)255;
    return p;
  };
  ushort* xb    = (ushort*)alloc((size_t)NPAD * 512 * 2);
  ushort* Pb    = (ushort*)alloc((size_t)NPAD * 512 * 2);
  ushort* Qb    = (ushort*)alloc((size_t)NPAD * 512 * 2);
  ushort* skipb = (ushort*)alloc((size_t)N_NODES * 512 * 2);
  ushort* hb    = (ushort*)alloc((size_t)N_NODES * 512 * 2);
  ushort* Bt1   = (ushort*)alloc((size_t)1024 * 512 * 2);
  ushort* Bt2   = (ushort*)alloc((size_t)1024 * 512 * 2);
  ushort* Bt3   = (ushort*)alloc((size_t)512 * 512 * 2);
  float*  a_sp  = (float*)alloc((size_t)N_NODES * 6 * 2 * 4);
  float*  a_dp  = (float*)alloc((size_t)N_NODES * 6 * 2 * 4);
  int*    cnt   = (int*)alloc((size_t)N_NODES * 4);
  int*    slots = (int*)alloc((size_t)N_NODES * CAP * 4);

  // ---- CSR slots ----
  hipMemsetAsync(cnt, 0, N_NODES * sizeof(int), stream);
  fill_csr_kernel<<<(E_TOT + 255) / 256, 256, 0, stream>>>(ei, cnt, slots);

  // ---- conversions / weight transposes ----
  convert_x_kernel<<<((NPAD * 512 / 4) + 255) / 256, 256, 0, stream>>>(x, xb);
  hipMemsetAsync(Pb + (size_t)N_NODES * 512, 0, (size_t)(NPAD - N_NODES) * 512 * 2, stream);
  hipMemsetAsync(Qb + (size_t)N_NODES * 512, 0, (size_t)(NPAD - N_NODES) * 512 * 2, stream);
  transpose_all_kernel<<<dim3(16, 16, 6), dim3(32, 8), 0, stream>>>(
      W1, lW1, W2, lW2, W3, lW3, Bt1, Bt2, Bt3);

  const int NBY = NPAD / 128;          // 157
  const int NWG12 = NBY * 8;           // 1256
  const int NWG3  = NBY * 4;           // 628

  // ---- layer 1 ----
  mfma_gemm_kernel<ushort><<<NWG12, 256, 0, stream>>>(
      xb, Bt1, hb, 512, 512, skipb, 512, 512, lb1, as1, ad1, a_sp, a_dp, 4, 128,
      NBY, NWG12);
  gather12_fused<4, 128><<<N_NODES, 128, 0, stream>>>(cnt, slots, a_sp, a_dp, hb, b1, skipb, Pb);

  // ---- layer 2 ----
  mfma_gemm_kernel<ushort><<<NWG12, 256, 0, stream>>>(
      Pb, Bt2, hb, 512, 512, skipb, 512, 512, lb2, as2, ad2, a_sp, a_dp, 4, 128,
      NBY, NWG12);
  gather12_fused<4, 128><<<N_NODES, 128, 0, stream>>>(cnt, slots, a_sp, a_dp, hb, b2, skipb, Qb);

  // ---- layer 3 ----
  mfma_gemm_kernel<float><<<NWG3, 256, 0, stream>>>(
      Qb, Bt3, hb, 384, 384, out, 64, 64, lb3, as3, ad3, a_sp, a_dp, 6, 64,
      NBY, NWG3);
  gather3_fused<<<N_NODES, 128, 0, stream>>>(cnt, slots, a_sp, a_dp, hb, b3, out);
}

// Round 8
// 305.924 us; speedup vs baseline: 1.2691x; 1.2691x over previous
//
#include <hip/hip_runtime.h>
#include <cstddef>
#include <cstdint>
#include <type_traits>

#define N_NODES 20000
#define NPAD 20096            // multiple of 128 for MFMA row tiles
#define E0_EDGES 160000
#define E_TOT (E0_EDGES + N_NODES)
#define CAP 64                // max in-degree slots (Poisson(9); P(>=64) ~ 0)

typedef __bf16 bf16x8 __attribute__((ext_vector_type(8)));
typedef float f32x4 __attribute__((ext_vector_type(4)));

__device__ __forceinline__ ushort f2bf(float f) {
  uint32_t u = __float_as_uint(f);
  return (ushort)((u + 0x7FFFu + ((u >> 16) & 1u)) >> 16);  // RNE
}
__device__ __forceinline__ float bf2f(ushort h) {
  return __uint_as_float((uint32_t)h << 16);
}

// chunk swizzle for 64B LDS rows
__device__ __forceinline__ int SW(int r) { return ((r >> 1) & 3) ^ ((r >> 3) & 1); }

// async global->LDS, 16B/lane; LDS dest = wave-uniform base + lane*16
#define GLOAD16(g, l)                                                         \
  __builtin_amdgcn_global_load_lds(                                           \
      (const __attribute__((address_space(1))) void*)(uintptr_t)(g),          \
      (__attribute__((address_space(3))) void*)(uint32_t)(uintptr_t)(l),      \
      16, 0, 0)

// ======================= CSR via fixed-stride slots ==========================

__global__ void fill_csr_kernel(const int* __restrict__ ei, int* __restrict__ cnt,
                                int* __restrict__ slots) {
  int e = blockIdx.x * blockDim.x + threadIdx.x;
  if (e >= E_TOT) return;
  int src, dst;
  if (e < E0_EDGES) { src = ei[e]; dst = ei[E0_EDGES + e]; }
  else              { src = e - E0_EDGES; dst = src; }
  int pos = atomicAdd(&cnt[dst], 1);
  if (pos < CAP) slots[dst * CAP + pos] = src;
}

// ======================= fp32 -> bf16 conversion =============================

__global__ void convert_x_kernel(const float* __restrict__ x, ushort* __restrict__ xb) {
  size_t i = ((size_t)blockIdx.x * blockDim.x + threadIdx.x) * 4;
  if (i >= (size_t)NPAD * 512) return;
  if (i < (size_t)N_NODES * 512) {
    float4 v = *(const float4*)(x + i);
    ushort4 o;
    o.x = f2bf(v.x); o.y = f2bf(v.y); o.z = f2bf(v.z); o.w = f2bf(v.w);
    *(ushort4*)(xb + i) = o;
  } else {
    *(ushort4*)(xb + i) = make_ushort4(0, 0, 0, 0);
  }
}

// Bt[m][k] = bf16(W[k][m]); all six weight matrices in one launch (z selects)
__global__ void transpose_all_kernel(
    const float* __restrict__ W1, const float* __restrict__ lW1,
    const float* __restrict__ W2, const float* __restrict__ lW2,
    const float* __restrict__ W3, const float* __restrict__ lW3,
    ushort* __restrict__ Bt1, ushort* __restrict__ Bt2, ushort* __restrict__ Bt3) {
  __shared__ float tile[32][33];
  const int K = 512;
  int z = blockIdx.z;
  const float* W; ushort* B; int M;
  switch (z) {
    case 0:  W = W1;  B = Bt1;              M = 512; break;
    case 1:  W = lW1; B = Bt1 + 512 * 512;  M = 512; break;
    case 2:  W = W2;  B = Bt2;              M = 512; break;
    case 3:  W = lW2; B = Bt2 + 512 * 512;  M = 512; break;
    case 4:  W = W3;  B = Bt3;              M = 384; break;
    default: W = lW3; B = Bt3 + 384 * 512;  M = 64;  break;
  }
  int mb = blockIdx.x * 32, kb = blockIdx.y * 32;
  if (mb >= M) return;
  int tx = threadIdx.x, ty = threadIdx.y;  // 32 x 8
#pragma unroll
  for (int i = 0; i < 32; i += 8)
    tile[ty + i][tx] = W[(size_t)(kb + ty + i) * M + mb + tx];
  __syncthreads();
#pragma unroll
  for (int i = 0; i < 32; i += 8)
    B[(size_t)(mb + ty + i) * K + kb + tx] = f2bf(tile[tx][ty + i]);
}

// ===== bf16 MFMA GEMM: 128x256 tile, 64x128/wave, 3-slot ring, BK=32 ========
// C[nrow x Ncols] = A @ Bt^T; cols<split -> out0 (bf16) + fused att scores;
// cols>=split -> out1 (+bias1). ONE barrier per K-step, counted vmcnt(6).

template <typename Out1T>
__global__ __launch_bounds__(256, 2) void mfma_gemm_kernel(
    const ushort* __restrict__ A,   // [NPAD][512] bf16
    const ushort* __restrict__ Bt,  // [colpad][512] bf16
    ushort* __restrict__ out0, int ld0, int split,
    Out1T* __restrict__ out1, int ld1, int Mout1, const float* __restrict__ bias1,
    const float* __restrict__ att_sw, const float* __restrict__ att_dw,  // [H][C]
    float* __restrict__ a_sp, float* __restrict__ a_dp,  // [N*H*2] parts
    int nheads, int headC,
    int NT, int nwg) {
  const int K = 512;
  __shared__ __attribute__((aligned(16))) ushort As[3][128][32];
  __shared__ __attribute__((aligned(16))) ushort Bs[3][256][32];

  // bijective XCD-chunked swizzle (m204); ROW-panel-major linearization.
  int q = nwg >> 3, r = nwg & 7;
  int orig = blockIdx.x;
  int xcd = orig & 7, pos = orig >> 3;
  int wgid = (xcd < r ? xcd * (q + 1) : r * (q + 1) + (xcd - r) * q) + pos;
  int by = wgid / NT, bx = wgid - by * NT;
  int bm = by * 128, bn = bx * 256;

  int tid = threadIdx.x, lane = tid & 63, wave = tid >> 6;
  int wrow = (wave >> 1) * 64, wcol = (wave & 1) * 128;

  size_t K2 = (size_t)K * 2;
  // staging: A rows [wave*32, +32) via 2 loads; B rows [wave*64, +64) via 4.
  // lane -> row lane>>2, LDS chunk lane&3; SOURCE chunk = (lane&3) ^ SW(row)
  int rofs = lane >> 2;
  int gch = (lane & 3) ^ SW(rofs);
  const char* pA[2];
  const char* pB[4];
  int arow[2], brow[4];
#pragma unroll
  for (int it = 0; it < 2; ++it) {
    arow[it] = wave * 32 + it * 16;
    pA[it] = (const char*)A + (size_t)(bm + arow[it] + rofs) * K2 + gch * 16;
  }
#pragma unroll
  for (int it = 0; it < 4; ++it) {
    brow[it] = wave * 64 + it * 16;
    pB[it] = (const char*)Bt + (size_t)(bn + brow[it] + rofs) * K2 + gch * 16;
  }

  int fr = lane & 15, hi = lane >> 4;
  int rch = hi ^ SW(fr);  // read-side swizzled chunk

  f32x4 acc[4][8] = {};

  char* AsB = (char*)&As[0][0][0];
  char* BsB = (char*)&Bs[0][0][0];

  // prologue: stage steps 0 and 1 (slots 0,1) -> 12 outstanding loads
#pragma unroll
  for (int s = 0; s < 2; ++s) {
#pragma unroll
    for (int it = 0; it < 2; ++it) GLOAD16(pA[it], AsB + s * 8192 + arow[it] * 64);
#pragma unroll
    for (int it = 0; it < 4; ++it) GLOAD16(pB[it], BsB + s * 16384 + brow[it] * 64);
#pragma unroll
    for (int it = 0; it < 2; ++it) pA[it] += 64;
#pragma unroll
    for (int it = 0; it < 4; ++it) pB[it] += 64;
  }

  const int KSTEPS = K >> 5;  // 16
  int s_cur = 0, s_stage = 2;
  for (int k = 0; k < KSTEPS; ++k) {
    if (k + 1 < KSTEPS) {
      asm volatile("s_waitcnt vmcnt(6)" ::: "memory");  // step-k loads landed
    } else {
      asm volatile("s_waitcnt vmcnt(0)" ::: "memory");
    }
    __builtin_amdgcn_s_barrier();   // all waves: step-k data ready; k-1 consumed
    asm volatile("" ::: "memory");
    if (k + 2 < KSTEPS) {           // stage step k+2 into ring slot
#pragma unroll
      for (int it = 0; it < 2; ++it) GLOAD16(pA[it], AsB + s_stage * 8192 + arow[it] * 64);
#pragma unroll
      for (int it = 0; it < 4; ++it) GLOAD16(pB[it], BsB + s_stage * 16384 + brow[it] * 64);
#pragma unroll
      for (int it = 0; it < 2; ++it) pA[it] += 64;
#pragma unroll
      for (int it = 0; it < 4; ++it) pB[it] += 64;
    }
    {
      bf16x8 af[4], bf[8];
#pragma unroll
      for (int i = 0; i < 4; ++i)
        af[i] = *(const bf16x8*)&As[s_cur][wrow + i * 16 + fr][rch * 8];
#pragma unroll
      for (int j = 0; j < 8; ++j)
        bf[j] = *(const bf16x8*)&Bs[s_cur][wcol + j * 16 + fr][rch * 8];
#pragma unroll
      for (int i = 0; i < 4; ++i)
#pragma unroll
        for (int j = 0; j < 8; ++j)
          acc[i][j] = __builtin_amdgcn_mfma_f32_16x16x32_bf16(af[i], bf[j], acc[i][j], 0, 0, 0);
    }
    asm volatile("" ::: "memory");
    s_cur = (s_cur == 2) ? 0 : s_cur + 1;
    s_stage = (s_stage == 2) ? 0 : s_stage + 1;
  }

  // ---- epilogue: C/D layout col=lane&15, row=(lane>>4)*4+reg [m89/m91] ----
  int colg = bn + wcol;            // 128-aligned, wave-uniform
  bool lower = colg < split;       // split is 128-aligned vs colg
  int g4 = hi << 2;
  int ccol = fr;
#pragma unroll
  for (int i = 0; i < 4; ++i) {
#pragma unroll
    for (int rr = 0; rr < 4; ++rr) {
      int row = bm + wrow + g4 + i * 16 + rr;
      if (row >= N_NODES) continue;
#pragma unroll
      for (int j = 0; j < 8; ++j) {
        int col = colg + j * 16 + ccol;
        float v = acc[i][j][rr];
        if (lower) {
          out0[(size_t)row * ld0 + col] = f2bf(v);
        } else {
          int c1 = col - split;
          if (c1 < Mout1) {
            float b = v + bias1[c1];
            if constexpr (std::is_same<Out1T, ushort>::value)
              out1[(size_t)row * ld1 + c1] = f2bf(b);
            else
              out1[(size_t)row * ld1 + c1] = b;
          }
        }
      }
    }
  }

  // ---- fused attention scores over this wave's 128 cols ----
  // headC==128: wave covers exactly one head. headC==64: exactly two heads.
  if (lower) {
    float ws8[8], wd8[8];
    int hd0;
    if (headC == 128) {
      hd0 = colg >> 7;
#pragma unroll
      for (int j = 0; j < 8; ++j) {
        int cc = hd0 * 128 + j * 16 + ccol;
        ws8[j] = att_sw[cc]; wd8[j] = att_dw[cc];
      }
    } else {
      hd0 = colg >> 6;
#pragma unroll
      for (int j = 0; j < 8; ++j) {
        int cc = (hd0 + (j >> 2)) * 64 + (j & 3) * 16 + ccol;
        ws8[j] = att_sw[cc]; wd8[j] = att_dw[cc];
      }
    }
#pragma unroll
    for (int i = 0; i < 4; ++i) {
#pragma unroll
      for (int rr = 0; rr < 4; ++rr) {
        if (headC == 128) {
          float ps = 0.f, pd = 0.f;
#pragma unroll
          for (int j = 0; j < 8; ++j) { ps += acc[i][j][rr] * ws8[j]; pd += acc[i][j][rr] * wd8[j]; }
#pragma unroll
          for (int o = 1; o < 16; o <<= 1) { ps += __shfl_xor(ps, o); pd += __shfl_xor(pd, o); }
          if ((lane & 15) == 0) {
            int row = bm + wrow + g4 + i * 16 + rr;
            if (row < N_NODES) {
              size_t idx = ((size_t)row * nheads + hd0) * 2;
              a_sp[idx] = ps; a_sp[idx + 1] = 0.f;
              a_dp[idx] = pd; a_dp[idx + 1] = 0.f;
            }
          }
        } else {
          float ps0 = 0.f, pd0 = 0.f, ps1 = 0.f, pd1 = 0.f;
#pragma unroll
          for (int j = 0; j < 4; ++j) { ps0 += acc[i][j][rr] * ws8[j]; pd0 += acc[i][j][rr] * wd8[j]; }
#pragma unroll
          for (int j = 4; j < 8; ++j) { ps1 += acc[i][j][rr] * ws8[j]; pd1 += acc[i][j][rr] * wd8[j]; }
#pragma unroll
          for (int o = 1; o < 16; o <<= 1) {
            ps0 += __shfl_xor(ps0, o); pd0 += __shfl_xor(pd0, o);
            ps1 += __shfl_xor(ps1, o); pd1 += __shfl_xor(pd1, o);
          }
          if ((lane & 15) == 0) {
            int row = bm + wrow + g4 + i * 16 + rr;
            if (row < N_NODES) {
              size_t i0 = ((size_t)row * nheads + hd0) * 2;
              size_t i1 = ((size_t)row * nheads + hd0 + 1) * 2;
              a_sp[i0] = ps0; a_sp[i0 + 1] = 0.f;
              a_dp[i0] = pd0; a_dp[i0 + 1] = 0.f;
              a_sp[i1] = ps1; a_sp[i1 + 1] = 0.f;
              a_dp[i1] = pd1; a_dp[i1 + 1] = 0.f;
            }
          }
        }
      }
    }
  }
}

// ======================= fused softmax + gather (layers 1,2) =================
// 128 threads: 2 waves do softmax for 2 heads each; then thread t owns
// features 4t..4t+3 (head = t>>5), 8B vector loads per edge.

template <int H, int C>
__global__ __launch_bounds__(128) void gather12_fused(
    const int* __restrict__ cnt, const int* __restrict__ slots,
    const float* __restrict__ a_sp, const float* __restrict__ a_dp,
    const ushort* __restrict__ hbuf, const float* __restrict__ gat_bias,
    const ushort* __restrict__ skip_in, ushort* __restrict__ outbuf) {
  __shared__ float al[H][CAP];
  __shared__ int srcs[CAP];
  int n = blockIdx.x;
  int t = threadIdx.x, lane = t & 63, w = t >> 6;  // 2 waves
  int deg = min(cnt[n], CAP);

  int sj = 0;
  if (lane < deg) sj = slots[n * CAP + lane];
#pragma unroll
  for (int hh = 0; hh < 2; ++hh) {
    int hd = 2 * w + hh;
    float e = -1e30f;
    if (lane < deg) {
      size_t is = ((size_t)sj * H + hd) * 2;
      size_t id = ((size_t)n * H + hd) * 2;
      float v = a_sp[is] + a_sp[is + 1] + a_dp[id] + a_dp[id + 1];
      e = v > 0.f ? v : 0.2f * v;  // leaky_relu
    }
    float m = e;
#pragma unroll
    for (int o = 32; o > 0; o >>= 1) m = fmaxf(m, __shfl_xor(m, o));
    float ex = (lane < deg) ? expf(e - m) : 0.f;
    float s = ex;
#pragma unroll
    for (int o = 32; o > 0; o >>= 1) s += __shfl_xor(s, o);
    float inv = 1.f / (s + 1e-16f);
    if (lane < deg) al[hd][lane] = ex * inv;
  }
  if (w == 0 && lane < deg) srcs[lane] = sj;
  __syncthreads();

  int f0 = 4 * t, hd = t >> 5;  // features 4t..4t+3, all in head t>>5
  float a0 = 0.f, a1 = 0.f, a2 = 0.f, a3 = 0.f;
  for (int j = 0; j < deg; ++j) {
    float a = al[hd][j];
    ushort4 hv = *(const ushort4*)(hbuf + (size_t)srcs[j] * (H * C) + f0);
    a0 += a * bf2f(hv.x);
    a1 += a * bf2f(hv.y);
    a2 += a * bf2f(hv.z);
    a3 += a * bf2f(hv.w);
  }
  ushort4 sk = *(const ushort4*)(skip_in + (size_t)n * (H * C) + f0);
  float o0 = a0 + gat_bias[f0 + 0] + bf2f(sk.x);
  float o1 = a1 + gat_bias[f0 + 1] + bf2f(sk.y);
  float o2 = a2 + gat_bias[f0 + 2] + bf2f(sk.z);
  float o3 = a3 + gat_bias[f0 + 3] + bf2f(sk.w);
  o0 = o0 > 0.f ? o0 : (expf(o0) - 1.f);  // ELU
  o1 = o1 > 0.f ? o1 : (expf(o1) - 1.f);
  o2 = o2 > 0.f ? o2 : (expf(o2) - 1.f);
  o3 = o3 > 0.f ? o3 : (expf(o3) - 1.f);
  ushort4 ov;
  ov.x = f2bf(o0); ov.y = f2bf(o1); ov.z = f2bf(o2); ov.w = f2bf(o3);
  *(ushort4*)(outbuf + (size_t)n * (H * C) + f0) = ov;
}

// ======================= fused softmax + gather (layer 3, mean heads) ========

__global__ __launch_bounds__(128) void gather3_fused(
    const int* __restrict__ cnt, const int* __restrict__ slots,
    const float* __restrict__ a_sp, const float* __restrict__ a_dp,
    const ushort* __restrict__ hbuf /*N x 384*/, const float* __restrict__ b3,
    float* __restrict__ out /*N x 64, holds skip+lb3*/) {
  __shared__ float al[6][CAP];
  __shared__ int srcs[CAP];
  __shared__ float part[2][64];
  int n = blockIdx.x;
  int t = threadIdx.x, lane = t & 63, w = t >> 6;
  int deg = min(cnt[n], CAP);

  int sj = 0;
  if (lane < deg) sj = slots[n * CAP + lane];
#pragma unroll
  for (int hh = 0; hh < 3; ++hh) {
    int hd = 3 * w + hh;
    float e = -1e30f;
    if (lane < deg) {
      size_t is = ((size_t)sj * 6 + hd) * 2;
      size_t id = ((size_t)n * 6 + hd) * 2;
      float v = a_sp[is] + a_sp[is + 1] + a_dp[id] + a_dp[id + 1];
      e = v > 0.f ? v : 0.2f * v;
    }
    float m = e;
#pragma unroll
    for (int o = 32; o > 0; o >>= 1) m = fmaxf(m, __shfl_xor(m, o));
    float ex = (lane < deg) ? expf(e - m) : 0.f;
    float s = ex;
#pragma unroll
    for (int o = 32; o > 0; o >>= 1) s += __shfl_xor(s, o);
    float inv = (1.f / 6.f) / (s + 1e-16f);  // fold mean over heads
    if (lane < deg) al[hd][lane] = ex * inv;
  }
  if (w == 0 && lane < deg) srcs[lane] = sj;
  __syncthreads();

  int c = t & 63;
  float acc = 0.f;
  for (int j = w; j < deg; j += 2) {
    const ushort* hr = hbuf + (size_t)srcs[j] * 384 + c;
#pragma unroll
    for (int hd = 0; hd < 6; ++hd) acc += al[hd][j] * bf2f(hr[hd * 64]);
  }
  part[w][c] = acc;
  __syncthreads();
  if (t < 64) {
    size_t oi = (size_t)n * 64 + t;
    out[oi] += part[0][t] + part[1][t] + b3[t];
  }
}

// ======================= host launch =========================================

extern "C" void kernel_launch(void* const* d_in, const int* in_sizes, int n_in,
                              void* d_out, int out_size, void* d_ws, size_t ws_size,
                              hipStream_t stream) {
  const float* x   = (const float*)d_in[0];
  const int*   ei  = (const int*)d_in[1];
  const float* W1  = (const float*)d_in[2];
  const float* as1 = (const float*)d_in[3];
  const float* ad1 = (const float*)d_in[4];
  const float* b1  = (const float*)d_in[5];
  const float* lW1 = (const float*)d_in[6];
  const float* lb1 = (const float*)d_in[7];
  const float* W2  = (const float*)d_in[8];
  const float* as2 = (const float*)d_in[9];
  const float* ad2 = (const float*)d_in[10];
  const float* b2  = (const float*)d_in[11];
  const float* lW2 = (const float*)d_in[12];
  const float* lb2 = (const float*)d_in[13];
  const float* W3  = (const float*)d_in[14];
  const float* as3 = (const float*)d_in[15];
  const float* ad3 = (const float*)d_in[16];
  const float* b3  = (const float*)d_in[17];
  const float* lW3 = (const float*)d_in[18];
  const float* lb3 = (const float*)d_in[19];
  float* out = (float*)d_out;

  char* ws = (char*)d_ws;
  auto alloc = [&](size_t bytes) -> void* {
    void* p = (void*)ws;
    ws += (bytes + 255) & ~(size_t)255;
    return p;
  };
  ushort* xb    = (ushort*)alloc((size_t)NPAD * 512 * 2);
  ushort* Pb    = (ushort*)alloc((size_t)NPAD * 512 * 2);
  ushort* Qb    = (ushort*)alloc((size_t)NPAD * 512 * 2);
  ushort* skipb = (ushort*)alloc((size_t)N_NODES * 512 * 2);
  ushort* hb    = (ushort*)alloc((size_t)N_NODES * 512 * 2);
  ushort* Bt1   = (ushort*)alloc((size_t)1024 * 512 * 2);
  ushort* Bt2   = (ushort*)alloc((size_t)1024 * 512 * 2);
  ushort* Bt3   = (ushort*)alloc((size_t)512 * 512 * 2);
  float*  a_sp  = (float*)alloc((size_t)N_NODES * 6 * 2 * 4);
  float*  a_dp  = (float*)alloc((size_t)N_NODES * 6 * 2 * 4);
  int*    cnt   = (int*)alloc((size_t)N_NODES * 4);
  int*    slots = (int*)alloc((size_t)N_NODES * CAP * 4);

  // ---- CSR slots ----
  hipMemsetAsync(cnt, 0, N_NODES * sizeof(int), stream);
  fill_csr_kernel<<<(E_TOT + 255) / 256, 256, 0, stream>>>(ei, cnt, slots);

  // ---- conversions / weight transposes ----
  convert_x_kernel<<<((NPAD * 512 / 4) + 255) / 256, 256, 0, stream>>>(x, xb);
  hipMemsetAsync(Pb + (size_t)N_NODES * 512, 0, (size_t)(NPAD - N_NODES) * 512 * 2, stream);
  hipMemsetAsync(Qb + (size_t)N_NODES * 512, 0, (size_t)(NPAD - N_NODES) * 512 * 2, stream);
  transpose_all_kernel<<<dim3(16, 16, 6), dim3(32, 8), 0, stream>>>(
      W1, lW1, W2, lW2, W3, lW3, Bt1, Bt2, Bt3);

  const int NBY = NPAD / 128;          // 157 row tiles
  const int NWG12 = NBY * 4;           // 628  (4 col tiles of 256)
  const int NWG3  = NBY * 2;           // 314  (2 col tiles of 256)

  // ---- layer 1 ----
  mfma_gemm_kernel<ushort><<<NWG12, 256, 0, stream>>>(
      xb, Bt1, hb, 512, 512, skipb, 512, 512, lb1, as1, ad1, a_sp, a_dp, 4, 128,
      4, NWG12);
  gather12_fused<4, 128><<<N_NODES, 128, 0, stream>>>(cnt, slots, a_sp, a_dp, hb, b1, skipb, Pb);

  // ---- layer 2 ----
  mfma_gemm_kernel<ushort><<<NWG12, 256, 0, stream>>>(
      Pb, Bt2, hb, 512, 512, skipb, 512, 512, lb2, as2, ad2, a_sp, a_dp, 4, 128,
      4, NWG12);
  gather12_fused<4, 128><<<N_NODES, 128, 0, stream>>>(cnt, slots, a_sp, a_dp, hb, b2, skipb, Qb);

  // ---- layer 3 ----
  mfma_gemm_kernel<float><<<NWG3, 256, 0, stream>>>(
      Qb, Bt3, hb, 384, 384, out, 64, 64, lb3, as3, ad3, a_sp, a_dp, 6, 64,
      2, NWG3);
  gather3_fused<<<N_NODES, 128, 0, stream>>>(cnt, slots, a_sp, a_dp, hb, b3, out);
}

// Round 10
// 285.634 us; speedup vs baseline: 1.3593x; 1.0710x over previous
//
#include <hip/hip_runtime.h>
#include <cstddef>
#include <cstdint>
#include <type_traits>

#define N_NODES 20000
#define NPAD 20096            // multiple of 128 for MFMA row tiles
#define E0_EDGES 160000
#define E_TOT (E0_EDGES + N_NODES)
#define CAP 64                // max in-degree slots (Poisson(9); P(>=64) ~ 0)

typedef __bf16 bf16x8 __attribute__((ext_vector_type(8)));
typedef float f32x4 __attribute__((ext_vector_type(4)));

__device__ __forceinline__ ushort f2bf(float f) {
  uint32_t u = __float_as_uint(f);
  return (ushort)((u + 0x7FFFu + ((u >> 16) & 1u)) >> 16);  // RNE
}
__device__ __forceinline__ float bf2f(ushort h) {
  return __uint_as_float((uint32_t)h << 16);
}

// chunk swizzle for 64B LDS rows
__device__ __forceinline__ int SW(int r) { return ((r >> 1) & 3) ^ ((r >> 3) & 1); }

// async global->LDS, 16B/lane; LDS dest = wave-uniform base + lane*16
#define GLOAD16(g, l)                                                         \
  __builtin_amdgcn_global_load_lds(                                           \
      (const __attribute__((address_space(1))) void*)(uintptr_t)(g),          \
      (__attribute__((address_space(3))) void*)(uint32_t)(uintptr_t)(l),      \
      16, 0, 0)

// ======================= CSR via fixed-stride slots ==========================

__global__ void fill_csr_kernel(const int* __restrict__ ei, int* __restrict__ cnt,
                                int* __restrict__ slots) {
  int e = blockIdx.x * blockDim.x + threadIdx.x;
  if (e >= E_TOT) return;
  int src, dst;
  if (e < E0_EDGES) { src = ei[e]; dst = ei[E0_EDGES + e]; }
  else              { src = e - E0_EDGES; dst = src; }
  int pos = atomicAdd(&cnt[dst], 1);
  if (pos < CAP) slots[dst * CAP + pos] = src;
}

// ======================= fp32 -> bf16 conversion =============================

__global__ void convert_x_kernel(const float* __restrict__ x, ushort* __restrict__ xb) {
  size_t i = ((size_t)blockIdx.x * blockDim.x + threadIdx.x) * 4;
  if (i >= (size_t)NPAD * 512) return;
  if (i < (size_t)N_NODES * 512) {
    float4 v = *(const float4*)(x + i);
    ushort4 o;
    o.x = f2bf(v.x); o.y = f2bf(v.y); o.z = f2bf(v.z); o.w = f2bf(v.w);
    *(ushort4*)(xb + i) = o;
  } else {
    *(ushort4*)(xb + i) = make_ushort4(0, 0, 0, 0);
  }
}

// Bt[m][k] = bf16(W[k][m]); all six weight matrices in one launch (z selects)
__global__ void transpose_all_kernel(
    const float* __restrict__ W1, const float* __restrict__ lW1,
    const float* __restrict__ W2, const float* __restrict__ lW2,
    const float* __restrict__ W3, const float* __restrict__ lW3,
    ushort* __restrict__ Bt1, ushort* __restrict__ Bt2, ushort* __restrict__ Bt3) {
  __shared__ float tile[32][33];
  const int K = 512;
  int z = blockIdx.z;
  const float* W; ushort* B; int M;
  switch (z) {
    case 0:  W = W1;  B = Bt1;              M = 512; break;
    case 1:  W = lW1; B = Bt1 + 512 * 512;  M = 512; break;
    case 2:  W = W2;  B = Bt2;              M = 512; break;
    case 3:  W = lW2; B = Bt2 + 512 * 512;  M = 512; break;
    case 4:  W = W3;  B = Bt3;              M = 384; break;
    default: W = lW3; B = Bt3 + 384 * 512;  M = 64;  break;
  }
  int mb = blockIdx.x * 32, kb = blockIdx.y * 32;
  if (mb >= M) return;
  int tx = threadIdx.x, ty = threadIdx.y;  // 32 x 8
#pragma unroll
  for (int i = 0; i < 32; i += 8)
    tile[ty + i][tx] = W[(size_t)(kb + ty + i) * M + mb + tx];
  __syncthreads();
#pragma unroll
  for (int i = 0; i < 32; i += 8)
    B[(size_t)(mb + ty + i) * K + kb + tx] = f2bf(tile[tx][ty + i]);
}

// ==== bf16 MFMA GEMM: 128x128, 4 waves, BK=32, 5-slot ring, 4-ahead =========
// C[nrow x Ncols] = A @ Bt^T; cols<split -> out0 (bf16) + fused att scores;
// cols>=split -> out1 (+bias1). ONE barrier per K-step; counted vmcnt ladder;
// lgkmcnt(0) drained BEFORE each barrier so slot reads complete before the
// post-barrier staging can overwrite that slot (m201-template safety).

template <typename Out1T>
__global__ __launch_bounds__(256, 2) void mfma_gemm_kernel(
    const ushort* __restrict__ A,   // [NPAD][512] bf16
    const ushort* __restrict__ Bt,  // [colpad][512] bf16
    ushort* __restrict__ out0, int ld0, int split,
    Out1T* __restrict__ out1, int ld1, int Mout1, const float* __restrict__ bias1,
    const float* __restrict__ att_sw, const float* __restrict__ att_dw,  // [H][C]
    float* __restrict__ a_sp, float* __restrict__ a_dp,  // [N*H*2] half-parts
    int nheads, int headC,
    int NT, int nwg) {
  const int K = 512;
  __shared__ __attribute__((aligned(16))) ushort As[5][128][32];
  __shared__ __attribute__((aligned(16))) ushort Bs[5][128][32];

  // bijective XCD-chunked swizzle (m204); row-panel-major linearization
  int q = nwg >> 3, r = nwg & 7;
  int orig = blockIdx.x;
  int xcd = orig & 7, pos = orig >> 3;
  int wgid = (xcd < r ? xcd * (q + 1) : r * (q + 1) + (xcd - r) * q) + pos;
  int by = wgid / NT, bx = wgid - by * NT;
  int bm = by * 128, bn = bx * 128;

  int tid = threadIdx.x, lane = tid & 63, wave = tid >> 6;
  int wrow = (wave >> 1) * 64, wcol = (wave & 1) * 64;

  size_t K2 = (size_t)K * 2;
  // staging: wave covers tile rows [wave*32, wave*32+32), 2 loads x 16 rows.
  // lane -> row lane>>2, LDS chunk lane&3; SOURCE chunk = (lane&3) ^ SW(row)
  int rofs = lane >> 2;
  int gch = (lane & 3) ^ SW(rofs);
  const char* pA[2];
  const char* pB[2];
  int srow[2];
#pragma unroll
  for (int it = 0; it < 2; ++it) {
    int rr = wave * 32 + it * 16 + rofs;
    srow[it] = wave * 32 + it * 16;
    pA[it] = (const char*)A + (size_t)(bm + rr) * K2 + gch * 16;
    pB[it] = (const char*)Bt + (size_t)(bn + rr) * K2 + gch * 16;
  }

  int fr = lane & 15, hi = lane >> 4;
  int rch = hi ^ SW(fr);  // read-side swizzled chunk

  f32x4 acc[4][4] = {};

  char* AsB = (char*)&As[0][0][0];
  char* BsB = (char*)&Bs[0][0][0];

  // prologue: stage steps 0..3 (slots 0..3) -> 16 outstanding loads/wave
#pragma unroll
  for (int s = 0; s < 4; ++s) {
#pragma unroll
    for (int it = 0; it < 2; ++it) {
      GLOAD16(pA[it], AsB + s * 8192 + srow[it] * 64);
      GLOAD16(pB[it], BsB + s * 8192 + srow[it] * 64);
    }
#pragma unroll
    for (int it = 0; it < 2; ++it) { pA[it] += 64; pB[it] += 64; }
  }

  // 16 K-steps, fully unrolled; slot k%5, stage (k+4)%5.
#pragma unroll
  for (int k = 0; k < 16; ++k) {
    // wait: step-k's 4 loads (oldest) landed AND all my LDS reads executed
    // (lgkmcnt(0) protects slot k-1 from the post-barrier overwrite below).
    if (k < 13)       asm volatile("s_waitcnt vmcnt(12) lgkmcnt(0)" ::: "memory");
    else if (k == 13) asm volatile("s_waitcnt vmcnt(8) lgkmcnt(0)"  ::: "memory");
    else if (k == 14) asm volatile("s_waitcnt vmcnt(4) lgkmcnt(0)"  ::: "memory");
    else              asm volatile("s_waitcnt vmcnt(0) lgkmcnt(0)"  ::: "memory");
    __builtin_amdgcn_s_barrier();   // step-k ready everywhere; k-1 fully read
    asm volatile("" ::: "memory");
    if (k + 4 < 16) {               // stage step k+4 (overwrites slot of k-1)
      int ss = (k + 4) % 5;
#pragma unroll
      for (int it = 0; it < 2; ++it) {
        GLOAD16(pA[it], AsB + ss * 8192 + srow[it] * 64);
        GLOAD16(pB[it], BsB + ss * 8192 + srow[it] * 64);
      }
#pragma unroll
      for (int it = 0; it < 2; ++it) { pA[it] += 64; pB[it] += 64; }
    }
    {
      int sc = k % 5;
      bf16x8 af[4], bf[4];
#pragma unroll
      for (int i = 0; i < 4; ++i)
        af[i] = *(const bf16x8*)&As[sc][wrow + i * 16 + fr][rch * 8];
#pragma unroll
      for (int j = 0; j < 4; ++j)
        bf[j] = *(const bf16x8*)&Bs[sc][wcol + j * 16 + fr][rch * 8];
#pragma unroll
      for (int i = 0; i < 4; ++i)
#pragma unroll
        for (int j = 0; j < 4; ++j)
          acc[i][j] = __builtin_amdgcn_mfma_f32_16x16x32_bf16(af[i], bf[j], acc[i][j], 0, 0, 0);
    }
    asm volatile("" ::: "memory");
  }

  // ---- epilogue: C/D layout col=lane&15, row=(lane>>4)*4+reg [m89/m91] ----
  int colg = bn + wcol;            // 64-aligned, wave-uniform
  bool lower = colg < split;
  int g4 = hi << 2;
  int ccol = fr;
#pragma unroll
  for (int i = 0; i < 4; ++i) {
#pragma unroll
    for (int rr = 0; rr < 4; ++rr) {
      int row = bm + wrow + g4 + i * 16 + rr;
      if (row >= N_NODES) continue;
#pragma unroll
      for (int j = 0; j < 4; ++j) {
        int col = colg + j * 16 + ccol;
        float v = acc[i][j][rr];
        if (lower) {
          out0[(size_t)row * ld0 + col] = f2bf(v);
        } else {
          int c1 = col - split;
          if (c1 < Mout1) {
            float b = v + bias1[c1];
            if constexpr (std::is_same<Out1T, ushort>::value)
              out1[(size_t)row * ld1 + c1] = f2bf(b);
            else
              out1[(size_t)row * ld1 + c1] = b;
          }
        }
      }
    }
  }

  // ---- fused attention scores: a_s/a_d = h . att over this wave's 64 cols ----
  // headC==128: wave covers half a head -> write part[half]; headC==64: whole
  // head -> write part[0], zero part[1]. Every slot written exactly once.
  if (lower) {
    int hd = colg / headC;               // wave-uniform head
    int cb = colg - hd * headC;          // 0 or 64
    int half = (cb >> 6) & 1;
    float ws4[4], wd4[4];
#pragma unroll
    for (int j = 0; j < 4; ++j) {
      int cc = hd * headC + cb + j * 16 + ccol;
      ws4[j] = att_sw[cc];
      wd4[j] = att_dw[cc];
    }
#pragma unroll
    for (int i = 0; i < 4; ++i) {
#pragma unroll
      for (int rr = 0; rr < 4; ++rr) {
        float ps = 0.f, pd = 0.f;
#pragma unroll
        for (int j = 0; j < 4; ++j) { ps += acc[i][j][rr] * ws4[j]; pd += acc[i][j][rr] * wd4[j]; }
#pragma unroll
        for (int o = 1; o < 16; o <<= 1) { ps += __shfl_xor(ps, o); pd += __shfl_xor(pd, o); }
        if ((lane & 15) == 0) {
          int row = bm + wrow + g4 + i * 16 + rr;
          if (row < N_NODES) {
            size_t idx = ((size_t)row * nheads + hd) * 2;
            if (headC == 128) {
              a_sp[idx + half] = ps;
              a_dp[idx + half] = pd;
            } else {
              a_sp[idx] = ps;  a_sp[idx + 1] = 0.f;
              a_dp[idx] = pd;  a_dp[idx + 1] = 0.f;
            }
          }
        }
      }
    }
  }
}

// ======================= fused softmax + gather (layers 1,2) =================
// 128 threads: 2 waves do softmax for 2 heads each; then thread t owns
// features 4t..4t+3 (head = t>>5), 8B vector loads per edge.

template <int H, int C>
__global__ __launch_bounds__(128) void gather12_fused(
    const int* __restrict__ cnt, const int* __restrict__ slots,
    const float* __restrict__ a_sp, const float* __restrict__ a_dp,
    const ushort* __restrict__ hbuf, const float* __restrict__ gat_bias,
    const ushort* __restrict__ skip_in, ushort* __restrict__ outbuf) {
  __shared__ float al[H][CAP];
  __shared__ int srcs[CAP];
  int n = blockIdx.x;
  int t = threadIdx.x, lane = t & 63, w = t >> 6;  // 2 waves
  int deg = min(cnt[n], CAP);

  int sj = 0;
  if (lane < deg) sj = slots[n * CAP + lane];
#pragma unroll
  for (int hh = 0; hh < 2; ++hh) {
    int hd = 2 * w + hh;
    float e = -1e30f;
    if (lane < deg) {
      size_t is = ((size_t)sj * H + hd) * 2;
      size_t id = ((size_t)n * H + hd) * 2;
      float v = a_sp[is] + a_sp[is + 1] + a_dp[id] + a_dp[id + 1];
      e = v > 0.f ? v : 0.2f * v;  // leaky_relu
    }
    float m = e;
#pragma unroll
    for (int o = 32; o > 0; o >>= 1) m = fmaxf(m, __shfl_xor(m, o));
    float ex = (lane < deg) ? expf(e - m) : 0.f;
    float s = ex;
#pragma unroll
    for (int o = 32; o > 0; o >>= 1) s += __shfl_xor(s, o);
    float inv = 1.f / (s + 1e-16f);
    if (lane < deg) al[hd][lane] = ex * inv;
  }
  if (w == 0 && lane < deg) srcs[lane] = sj;
  __syncthreads();

  int f0 = 4 * t, hd = t >> 5;  // features 4t..4t+3, all in head t>>5
  float a0 = 0.f, a1 = 0.f, a2 = 0.f, a3 = 0.f;
  for (int j = 0; j < deg; ++j) {
    float a = al[hd][j];
    ushort4 hv = *(const ushort4*)(hbuf + (size_t)srcs[j] * (H * C) + f0);
    a0 += a * bf2f(hv.x);
    a1 += a * bf2f(hv.y);
    a2 += a * bf2f(hv.z);
    a3 += a * bf2f(hv.w);
  }
  ushort4 sk = *(const ushort4*)(skip_in + (size_t)n * (H * C) + f0);
  float o0 = a0 + gat_bias[f0 + 0] + bf2f(sk.x);
  float o1 = a1 + gat_bias[f0 + 1] + bf2f(sk.y);
  float o2 = a2 + gat_bias[f0 + 2] + bf2f(sk.z);
  float o3 = a3 + gat_bias[f0 + 3] + bf2f(sk.w);
  o0 = o0 > 0.f ? o0 : (expf(o0) - 1.f);  // ELU
  o1 = o1 > 0.f ? o1 : (expf(o1) - 1.f);
  o2 = o2 > 0.f ? o2 : (expf(o2) - 1.f);
  o3 = o3 > 0.f ? o3 : (expf(o3) - 1.f);
  ushort4 ov;
  ov.x = f2bf(o0); ov.y = f2bf(o1); ov.z = f2bf(o2); ov.w = f2bf(o3);
  *(ushort4*)(outbuf + (size_t)n * (H * C) + f0) = ov;
}

// ======================= fused softmax + gather (layer 3, mean heads) ========

__global__ __launch_bounds__(128) void gather3_fused(
    const int* __restrict__ cnt, const int* __restrict__ slots,
    const float* __restrict__ a_sp, const float* __restrict__ a_dp,
    const ushort* __restrict__ hbuf /*N x 384*/, const float* __restrict__ b3,
    float* __restrict__ out /*N x 64, holds skip+lb3*/) {
  __shared__ float al[6][CAP];
  __shared__ int srcs[CAP];
  __shared__ float part[2][64];
  int n = blockIdx.x;
  int t = threadIdx.x, lane = t & 63, w = t >> 6;
  int deg = min(cnt[n], CAP);

  int sj = 0;
  if (lane < deg) sj = slots[n * CAP + lane];
#pragma unroll
  for (int hh = 0; hh < 3; ++hh) {
    int hd = 3 * w + hh;
    float e = -1e30f;
    if (lane < deg) {
      size_t is = ((size_t)sj * 6 + hd) * 2;
      size_t id = ((size_t)n * 6 + hd) * 2;
      float v = a_sp[is] + a_sp[is + 1] + a_dp[id] + a_dp[id + 1];
      e = v > 0.f ? v : 0.2f * v;
    }
    float m = e;
#pragma unroll
    for (int o = 32; o > 0; o >>= 1) m = fmaxf(m, __shfl_xor(m, o));
    float ex = (lane < deg) ? expf(e - m) : 0.f;
    float s = ex;
#pragma unroll
    for (int o = 32; o > 0; o >>= 1) s += __shfl_xor(s, o);
    float inv = (1.f / 6.f) / (s + 1e-16f);  // fold mean over heads
    if (lane < deg) al[hd][lane] = ex * inv;
  }
  if (w == 0 && lane < deg) srcs[lane] = sj;
  __syncthreads();

  int c = t & 63;
  float acc = 0.f;
  for (int j = w; j < deg; j += 2) {
    const ushort* hr = hbuf + (size_t)srcs[j] * 384 + c;
#pragma unroll
    for (int hd = 0; hd < 6; ++hd) acc += al[hd][j] * bf2f(hr[hd * 64]);
  }
  part[w][c] = acc;
  __syncthreads();
  if (t < 64) {
    size_t oi = (size_t)n * 64 + t;
    out[oi] += part[0][t] + part[1][t] + b3[t];
  }
}

// ======================= host launch =========================================

extern "C" void kernel_launch(void* const* d_in, const int* in_sizes, int n_in,
                              void* d_out, int out_size, void* d_ws, size_t ws_size,
                              hipStream_t stream) {
  const float* x   = (const float*)d_in[0];
  const int*   ei  = (const int*)d_in[1];
  const float* W1  = (const float*)d_in[2];
  const float* as1 = (const float*)d_in[3];
  const float* ad1 = (const float*)d_in[4];
  const float* b1  = (const float*)d_in[5];
  const float* lW1 = (const float*)d_in[6];
  const float* lb1 = (const float*)d_in[7];
  const float* W2  = (const float*)d_in[8];
  const float* as2 = (const float*)d_in[9];
  const float* ad2 = (const float*)d_in[10];
  const float* b2  = (const float*)d_in[11];
  const float* lW2 = (const float*)d_in[12];
  const float* lb2 = (const float*)d_in[13];
  const float* W3  = (const float*)d_in[14];
  const float* as3 = (const float*)d_in[15];
  const float* ad3 = (const float*)d_in[16];
  const float* b3  = (const float*)d_in[17];
  const float* lW3 = (const float*)d_in[18];
  const float* lb3 = (const float*)d_in[19];
  float* out = (float*)d_out;

  char* ws = (char*)d_ws;
  auto alloc = [&](size_t bytes) -> void* {
    void* p = (void*)ws;
    ws += (bytes + 255) & ~(size_t)255;
    return p;
  };
  ushort* xb    = (ushort*)alloc((size_t)NPAD * 512 * 2);
  ushort* Pb    = (ushort*)alloc((size_t)NPAD * 512 * 2);
  ushort* Qb    = (ushort*)alloc((size_t)NPAD * 512 * 2);
  ushort* skipb = (ushort*)alloc((size_t)N_NODES * 512 * 2);
  ushort* hb    = (ushort*)alloc((size_t)N_NODES * 512 * 2);
  ushort* Bt1   = (ushort*)alloc((size_t)1024 * 512 * 2);
  ushort* Bt2   = (ushort*)alloc((size_t)1024 * 512 * 2);
  ushort* Bt3   = (ushort*)alloc((size_t)512 * 512 * 2);
  float*  a_sp  = (float*)alloc((size_t)N_NODES * 6 * 2 * 4);
  float*  a_dp  = (float*)alloc((size_t)N_NODES * 6 * 2 * 4);
  int*    cnt   = (int*)alloc((size_t)N_NODES * 4);
  int*    slots = (int*)alloc((size_t)N_NODES * CAP * 4);

  // ---- CSR slots ----
  hipMemsetAsync(cnt, 0, N_NODES * sizeof(int), stream);
  fill_csr_kernel<<<(E_TOT + 255) / 256, 256, 0, stream>>>(ei, cnt, slots);

  // ---- conversions / weight transposes ----
  convert_x_kernel<<<((NPAD * 512 / 4) + 255) / 256, 256, 0, stream>>>(x, xb);
  hipMemsetAsync(Pb + (size_t)N_NODES * 512, 0, (size_t)(NPAD - N_NODES) * 512 * 2, stream);
  hipMemsetAsync(Qb + (size_t)N_NODES * 512, 0, (size_t)(NPAD - N_NODES) * 512 * 2, stream);
  transpose_all_kernel<<<dim3(16, 16, 6), dim3(32, 8), 0, stream>>>(
      W1, lW1, W2, lW2, W3, lW3, Bt1, Bt2, Bt3);

  const int NBY = NPAD / 128;          // 157 row tiles
  const int NWG12 = NBY * 8;           // 1256 (8 col tiles of 128)
  const int NWG3  = NBY * 4;           // 628  (4 col tiles of 128)

  // ---- layer 1 ----
  mfma_gemm_kernel<ushort><<<NWG12, 256, 0, stream>>>(
      xb, Bt1, hb, 512, 512, skipb, 512, 512, lb1, as1, ad1, a_sp, a_dp, 4, 128,
      8, NWG12);
  gather12_fused<4, 128><<<N_NODES, 128, 0, stream>>>(cnt, slots, a_sp, a_dp, hb, b1, skipb, Pb);

  // ---- layer 2 ----
  mfma_gemm_kernel<ushort><<<NWG12, 256, 0, stream>>>(
      Pb, Bt2, hb, 512, 512, skipb, 512, 512, lb2, as2, ad2, a_sp, a_dp, 4, 128,
      8, NWG12);
  gather12_fused<4, 128><<<N_NODES, 128, 0, stream>>>(cnt, slots, a_sp, a_dp, hb, b2, skipb, Qb);

  // ---- layer 3 ----
  mfma_gemm_kernel<float><<<NWG3, 256, 0, stream>>>(
      Qb, Bt3, hb, 384, 384, out, 64, 64, lb3, as3, ad3, a_sp, a_dp, 6, 64,
      4, NWG3);
  gather3_fused<<<N_NODES, 128, 0, stream>>>(cnt, slots, a_sp, a_dp, hb, b3, out);
}

// Round 11
// 258.994 us; speedup vs baseline: 1.4991x; 1.1029x over previous
//
#include <hip/hip_runtime.h>
#include <cstddef>
#include <cstdint>
#include <type_traits>

#define N_NODES 20000
#define NPAD 20096            // multiple of 128 for MFMA row tiles
#define E0_EDGES 160000
#define E_TOT (E0_EDGES + N_NODES)
#define CAP 64                // max in-degree slots (Poisson(9); P(>=64) ~ 0)

typedef __bf16 bf16x8 __attribute__((ext_vector_type(8)));
typedef float f32x4 __attribute__((ext_vector_type(4)));

__device__ __forceinline__ ushort f2bf(float f) {
  uint32_t u = __float_as_uint(f);
  return (ushort)((u + 0x7FFFu + ((u >> 16) & 1u)) >> 16);  // RNE
}
__device__ __forceinline__ float bf2f(ushort h) {
  return __uint_as_float((uint32_t)h << 16);
}

// chunk swizzle for 64B LDS rows
__device__ __forceinline__ int SW(int r) { return ((r >> 1) & 3) ^ ((r >> 3) & 1); }

// async global->LDS, 16B/lane; LDS dest = wave-uniform base + lane*16
#define GLOAD16(g, l)                                                         \
  __builtin_amdgcn_global_load_lds(                                           \
      (const __attribute__((address_space(1))) void*)(uintptr_t)(g),          \
      (__attribute__((address_space(3))) void*)(uint32_t)(uintptr_t)(l),      \
      16, 0, 0)

// ======================= CSR via fixed-stride slots ==========================

__global__ void fill_csr_kernel(const int* __restrict__ ei, int* __restrict__ cnt,
                                int* __restrict__ slots) {
  int e = blockIdx.x * blockDim.x + threadIdx.x;
  if (e >= E_TOT) return;
  int src, dst;
  if (e < E0_EDGES) { src = ei[e]; dst = ei[E0_EDGES + e]; }
  else              { src = e - E0_EDGES; dst = src; }
  int pos = atomicAdd(&cnt[dst], 1);
  if (pos < CAP) slots[dst * CAP + pos] = src;
}

// ======================= fp32 -> bf16 conversion =============================

__global__ void convert_x_kernel(const float* __restrict__ x, ushort* __restrict__ xb) {
  size_t i = ((size_t)blockIdx.x * blockDim.x + threadIdx.x) * 4;
  if (i >= (size_t)NPAD * 512) return;
  if (i < (size_t)N_NODES * 512) {
    float4 v = *(const float4*)(x + i);
    ushort4 o;
    o.x = f2bf(v.x); o.y = f2bf(v.y); o.z = f2bf(v.z); o.w = f2bf(v.w);
    *(ushort4*)(xb + i) = o;
  } else {
    *(ushort4*)(xb + i) = make_ushort4(0, 0, 0, 0);
  }
}

// Bt[m][k] = bf16(W[k][m]); all six weight matrices in one launch (z selects)
__global__ void transpose_all_kernel(
    const float* __restrict__ W1, const float* __restrict__ lW1,
    const float* __restrict__ W2, const float* __restrict__ lW2,
    const float* __restrict__ W3, const float* __restrict__ lW3,
    ushort* __restrict__ Bt1, ushort* __restrict__ Bt2, ushort* __restrict__ Bt3) {
  __shared__ float tile[32][33];
  const int K = 512;
  int z = blockIdx.z;
  const float* W; ushort* B; int M;
  switch (z) {
    case 0:  W = W1;  B = Bt1;              M = 512; break;
    case 1:  W = lW1; B = Bt1 + 512 * 512;  M = 512; break;
    case 2:  W = W2;  B = Bt2;              M = 512; break;
    case 3:  W = lW2; B = Bt2 + 512 * 512;  M = 512; break;
    case 4:  W = W3;  B = Bt3;              M = 384; break;
    default: W = lW3; B = Bt3 + 384 * 512;  M = 64;  break;
  }
  int mb = blockIdx.x * 32, kb = blockIdx.y * 32;
  if (mb >= M) return;
  int tx = threadIdx.x, ty = threadIdx.y;  // 32 x 8
#pragma unroll
  for (int i = 0; i < 32; i += 8)
    tile[ty + i][tx] = W[(size_t)(kb + ty + i) * M + mb + tx];
  __syncthreads();
#pragma unroll
  for (int i = 0; i < 32; i += 8)
    B[(size_t)(mb + ty + i) * K + kb + tx] = f2bf(tile[tx][ty + i]);
}

// ==== bf16 MFMA GEMM: persistent blocks, 128x128 tile, BK=32, 3-slot ring ===
// C[nrow x Ncols] = A @ Bt^T; cols<split -> out0 (bf16) + fused att scores;
// cols>=split -> out1 (+bias1). ONE barrier per K-step; counted vmcnt(4);
// lgkmcnt(0) drained before every barrier (slot-reuse safety, m201 template);
// extra lgkm+barrier at tile seam so next-tile prologue can't overwrite slot 0.

template <typename Out1T>
__global__ __launch_bounds__(256, 3) void mfma_gemm_kernel(
    const ushort* __restrict__ A,   // [NPAD][512] bf16
    const ushort* __restrict__ Bt,  // [colpad][512] bf16
    ushort* __restrict__ out0, int ld0, int split,
    Out1T* __restrict__ out1, int ld1, int Mout1, const float* __restrict__ bias1,
    const float* __restrict__ att_sw, const float* __restrict__ att_dw,  // [H][C]
    float* __restrict__ a_sp, float* __restrict__ a_dp,  // [N*H*2] half-parts
    int nheads, int headC,
    int NT, int nwg) {
  const int K = 512;
  __shared__ __attribute__((aligned(16))) ushort As[3][128][32];
  __shared__ __attribute__((aligned(16))) ushort Bs[3][128][32];

  int tid = threadIdx.x, lane = tid & 63, wave = tid >> 6;
  int wrow = (wave >> 1) * 64, wcol = (wave & 1) * 64;

  size_t K2 = (size_t)K * 2;
  // staging: wave covers tile rows [wave*32, wave*32+32), 2 loads x 16 rows.
  // lane -> row lane>>2, LDS chunk lane&3; SOURCE chunk = (lane&3) ^ SW(row)
  int rofs = lane >> 2;
  int gch = (lane & 3) ^ SW(rofs);
  int srow[2];
#pragma unroll
  for (int it = 0; it < 2; ++it) srow[it] = wave * 32 + it * 16;

  int fr = lane & 15, hi = lane >> 4;
  int rch = hi ^ SW(fr);  // read-side swizzled chunk

  char* AsB = (char*)&As[0][0][0];
  char* BsB = (char*)&Bs[0][0][0];

  int q = nwg >> 3, r = nwg & 7;

  for (int w0 = blockIdx.x; w0 < nwg; w0 += gridDim.x) {
    // bijective XCD-chunked swizzle (m204); row-panel-major linearization
    int xcd = w0 & 7, pos = w0 >> 3;
    int wgid = (xcd < r ? xcd * (q + 1) : r * (q + 1) + (xcd - r) * q) + pos;
    int by = wgid / NT, bx = wgid - by * NT;
    int bm = by * 128, bn = bx * 128;

    const char* pA[2];
    const char* pB[2];
#pragma unroll
    for (int it = 0; it < 2; ++it) {
      pA[it] = (const char*)A + (size_t)(bm + srow[it] + rofs) * K2 + gch * 16;
      pB[it] = (const char*)Bt + (size_t)(bn + srow[it] + rofs) * K2 + gch * 16;
    }

    f32x4 acc[4][4] = {};

    // prologue: stage steps 0 and 1 (slots 0,1) -> 8 outstanding loads/wave
#pragma unroll
    for (int s = 0; s < 2; ++s) {
#pragma unroll
      for (int it = 0; it < 2; ++it) {
        GLOAD16(pA[it], AsB + s * 8192 + srow[it] * 64);
        GLOAD16(pB[it], BsB + s * 8192 + srow[it] * 64);
      }
#pragma unroll
      for (int it = 0; it < 2; ++it) { pA[it] += 64; pB[it] += 64; }
    }

    // 16 K-steps; slot k%3, stage (k+2)%3 after the barrier.
    for (int k = 0; k < 16; ++k) {
      // step-k loads (oldest 4) landed; my LDS reads of k-1 fully executed.
      if (k + 1 < 16) asm volatile("s_waitcnt vmcnt(4) lgkmcnt(0)" ::: "memory");
      else            asm volatile("s_waitcnt vmcnt(0) lgkmcnt(0)" ::: "memory");
      __builtin_amdgcn_s_barrier();   // step-k ready everywhere; k-1 consumed
      asm volatile("" ::: "memory");
      if (k + 2 < 16) {               // stage step k+2 (overwrites slot of k-1)
        int ss = (k + 2) % 3;
#pragma unroll
        for (int it = 0; it < 2; ++it) {
          GLOAD16(pA[it], AsB + ss * 8192 + srow[it] * 64);
          GLOAD16(pB[it], BsB + ss * 8192 + srow[it] * 64);
        }
#pragma unroll
        for (int it = 0; it < 2; ++it) { pA[it] += 64; pB[it] += 64; }
      }
      {
        int sc = k % 3;
        bf16x8 af[4], bf[4];
#pragma unroll
        for (int i = 0; i < 4; ++i)
          af[i] = *(const bf16x8*)&As[sc][wrow + i * 16 + fr][rch * 8];
#pragma unroll
        for (int j = 0; j < 4; ++j)
          bf[j] = *(const bf16x8*)&Bs[sc][wcol + j * 16 + fr][rch * 8];
#pragma unroll
        for (int i = 0; i < 4; ++i)
#pragma unroll
          for (int j = 0; j < 4; ++j)
            acc[i][j] = __builtin_amdgcn_mfma_f32_16x16x32_bf16(af[i], bf[j], acc[i][j], 0, 0, 0);
      }
      asm volatile("" ::: "memory");
    }

    // tile seam: all waves' step-15 LDS reads done before next prologue stages
    asm volatile("s_waitcnt lgkmcnt(0)" ::: "memory");
    __builtin_amdgcn_s_barrier();
    asm volatile("" ::: "memory");

    // ---- epilogue: C/D layout col=lane&15, row=(lane>>4)*4+reg [m89/m91] ----
    int colg = bn + wcol;            // 64-aligned, wave-uniform
    bool lower = colg < split;
    int g4 = hi << 2;
    int ccol = fr;
#pragma unroll
    for (int i = 0; i < 4; ++i) {
#pragma unroll
      for (int rr = 0; rr < 4; ++rr) {
        int row = bm + wrow + g4 + i * 16 + rr;
        if (row >= N_NODES) continue;
#pragma unroll
        for (int j = 0; j < 4; ++j) {
          int col = colg + j * 16 + ccol;
          float v = acc[i][j][rr];
          if (lower) {
            out0[(size_t)row * ld0 + col] = f2bf(v);
          } else {
            int c1 = col - split;
            if (c1 < Mout1) {
              float b = v + bias1[c1];
              if constexpr (std::is_same<Out1T, ushort>::value)
                out1[(size_t)row * ld1 + c1] = f2bf(b);
              else
                out1[(size_t)row * ld1 + c1] = b;
            }
          }
        }
      }
    }

    // ---- fused attention scores: a_s/a_d = h . att over this wave's 64 cols --
    if (lower) {
      int hd = colg / headC;               // wave-uniform head
      int cb = colg - hd * headC;          // 0 or 64
      int half = (cb >> 6) & 1;
      float ws4[4], wd4[4];
#pragma unroll
      for (int j = 0; j < 4; ++j) {
        int cc = hd * headC + cb + j * 16 + ccol;
        ws4[j] = att_sw[cc];
        wd4[j] = att_dw[cc];
      }
#pragma unroll
      for (int i = 0; i < 4; ++i) {
#pragma unroll
        for (int rr = 0; rr < 4; ++rr) {
          float ps = 0.f, pd = 0.f;
#pragma unroll
          for (int j = 0; j < 4; ++j) { ps += acc[i][j][rr] * ws4[j]; pd += acc[i][j][rr] * wd4[j]; }
#pragma unroll
          for (int o = 1; o < 16; o <<= 1) { ps += __shfl_xor(ps, o); pd += __shfl_xor(pd, o); }
          if ((lane & 15) == 0) {
            int row = bm + wrow + g4 + i * 16 + rr;
            if (row < N_NODES) {
              size_t idx = ((size_t)row * nheads + hd) * 2;
              if (headC == 128) {
                a_sp[idx + half] = ps;
                a_dp[idx + half] = pd;
              } else {
                a_sp[idx] = ps;  a_sp[idx + 1] = 0.f;
                a_dp[idx] = pd;  a_dp[idx + 1] = 0.f;
              }
            }
          }
        }
      }
    }
  }
}

// ======================= fused softmax + gather (layers 1,2) =================
// 128 threads: 2 waves do softmax for 2 heads each; then thread t owns
// features 4t..4t+3 (head = t>>5), 8B vector loads per edge.

template <int H, int C>
__global__ __launch_bounds__(128) void gather12_fused(
    const int* __restrict__ cnt, const int* __restrict__ slots,
    const float* __restrict__ a_sp, const float* __restrict__ a_dp,
    const ushort* __restrict__ hbuf, const float* __restrict__ gat_bias,
    const ushort* __restrict__ skip_in, ushort* __restrict__ outbuf) {
  __shared__ float al[H][CAP];
  __shared__ int srcs[CAP];
  int n = blockIdx.x;
  int t = threadIdx.x, lane = t & 63, w = t >> 6;  // 2 waves
  int deg = min(cnt[n], CAP);

  int sj = 0;
  if (lane < deg) sj = slots[n * CAP + lane];
#pragma unroll
  for (int hh = 0; hh < 2; ++hh) {
    int hd = 2 * w + hh;
    float e = -1e30f;
    if (lane < deg) {
      size_t is = ((size_t)sj * H + hd) * 2;
      size_t id = ((size_t)n * H + hd) * 2;
      float v = a_sp[is] + a_sp[is + 1] + a_dp[id] + a_dp[id + 1];
      e = v > 0.f ? v : 0.2f * v;  // leaky_relu
    }
    float m = e;
#pragma unroll
    for (int o = 32; o > 0; o >>= 1) m = fmaxf(m, __shfl_xor(m, o));
    float ex = (lane < deg) ? expf(e - m) : 0.f;
    float s = ex;
#pragma unroll
    for (int o = 32; o > 0; o >>= 1) s += __shfl_xor(s, o);
    float inv = 1.f / (s + 1e-16f);
    if (lane < deg) al[hd][lane] = ex * inv;
  }
  if (w == 0 && lane < deg) srcs[lane] = sj;
  __syncthreads();

  int f0 = 4 * t, hd = t >> 5;  // features 4t..4t+3, all in head t>>5
  float a0 = 0.f, a1 = 0.f, a2 = 0.f, a3 = 0.f;
  for (int j = 0; j < deg; ++j) {
    float a = al[hd][j];
    ushort4 hv = *(const ushort4*)(hbuf + (size_t)srcs[j] * (H * C) + f0);
    a0 += a * bf2f(hv.x);
    a1 += a * bf2f(hv.y);
    a2 += a * bf2f(hv.z);
    a3 += a * bf2f(hv.w);
  }
  ushort4 sk = *(const ushort4*)(skip_in + (size_t)n * (H * C) + f0);
  float o0 = a0 + gat_bias[f0 + 0] + bf2f(sk.x);
  float o1 = a1 + gat_bias[f0 + 1] + bf2f(sk.y);
  float o2 = a2 + gat_bias[f0 + 2] + bf2f(sk.z);
  float o3 = a3 + gat_bias[f0 + 3] + bf2f(sk.w);
  o0 = o0 > 0.f ? o0 : (expf(o0) - 1.f);  // ELU
  o1 = o1 > 0.f ? o1 : (expf(o1) - 1.f);
  o2 = o2 > 0.f ? o2 : (expf(o2) - 1.f);
  o3 = o3 > 0.f ? o3 : (expf(o3) - 1.f);
  ushort4 ov;
  ov.x = f2bf(o0); ov.y = f2bf(o1); ov.z = f2bf(o2); ov.w = f2bf(o3);
  *(ushort4*)(outbuf + (size_t)n * (H * C) + f0) = ov;
}

// ======================= fused softmax + gather (layer 3, mean heads) ========

__global__ __launch_bounds__(128) void gather3_fused(
    const int* __restrict__ cnt, const int* __restrict__ slots,
    const float* __restrict__ a_sp, const float* __restrict__ a_dp,
    const ushort* __restrict__ hbuf /*N x 384*/, const float* __restrict__ b3,
    float* __restrict__ out /*N x 64, holds skip+lb3*/) {
  __shared__ float al[6][CAP];
  __shared__ int srcs[CAP];
  __shared__ float part[2][64];
  int n = blockIdx.x;
  int t = threadIdx.x, lane = t & 63, w = t >> 6;
  int deg = min(cnt[n], CAP);

  int sj = 0;
  if (lane < deg) sj = slots[n * CAP + lane];
#pragma unroll
  for (int hh = 0; hh < 3; ++hh) {
    int hd = 3 * w + hh;
    float e = -1e30f;
    if (lane < deg) {
      size_t is = ((size_t)sj * 6 + hd) * 2;
      size_t id = ((size_t)n * 6 + hd) * 2;
      float v = a_sp[is] + a_sp[is + 1] + a_dp[id] + a_dp[id + 1];
      e = v > 0.f ? v : 0.2f * v;
    }
    float m = e;
#pragma unroll
    for (int o = 32; o > 0; o >>= 1) m = fmaxf(m, __shfl_xor(m, o));
    float ex = (lane < deg) ? expf(e - m) : 0.f;
    float s = ex;
#pragma unroll
    for (int o = 32; o > 0; o >>= 1) s += __shfl_xor(s, o);
    float inv = (1.f / 6.f) / (s + 1e-16f);  // fold mean over heads
    if (lane < deg) al[hd][lane] = ex * inv;
  }
  if (w == 0 && lane < deg) srcs[lane] = sj;
  __syncthreads();

  int c = t & 63;
  float acc = 0.f;
  for (int j = w; j < deg; j += 2) {
    const ushort* hr = hbuf + (size_t)srcs[j] * 384 + c;
#pragma unroll
    for (int hd = 0; hd < 6; ++hd) acc += al[hd][j] * bf2f(hr[hd * 64]);
  }
  part[w][c] = acc;
  __syncthreads();
  if (t < 64) {
    size_t oi = (size_t)n * 64 + t;
    out[oi] += part[0][t] + part[1][t] + b3[t];
  }
}

// ======================= host launch =========================================

extern "C" void kernel_launch(void* const* d_in, const int* in_sizes, int n_in,
                              void* d_out, int out_size, void* d_ws, size_t ws_size,
                              hipStream_t stream) {
  const float* x   = (const float*)d_in[0];
  const int*   ei  = (const int*)d_in[1];
  const float* W1  = (const float*)d_in[2];
  const float* as1 = (const float*)d_in[3];
  const float* ad1 = (const float*)d_in[4];
  const float* b1  = (const float*)d_in[5];
  const float* lW1 = (const float*)d_in[6];
  const float* lb1 = (const float*)d_in[7];
  const float* W2  = (const float*)d_in[8];
  const float* as2 = (const float*)d_in[9];
  const float* ad2 = (const float*)d_in[10];
  const float* b2  = (const float*)d_in[11];
  const float* lW2 = (const float*)d_in[12];
  const float* lb2 = (const float*)d_in[13];
  const float* W3  = (const float*)d_in[14];
  const float* as3 = (const float*)d_in[15];
  const float* ad3 = (const float*)d_in[16];
  const float* b3  = (const float*)d_in[17];
  const float* lW3 = (const float*)d_in[18];
  const float* lb3 = (const float*)d_in[19];
  float* out = (float*)d_out;

  char* ws = (char*)d_ws;
  auto alloc = [&](size_t bytes) -> void* {
    void* p = (void*)ws;
    ws += (bytes + 255) & ~(size_t)255;
    return p;
  };
  ushort* xb    = (ushort*)alloc((size_t)NPAD * 512 * 2);
  ushort* Pb    = (ushort*)alloc((size_t)NPAD * 512 * 2);
  ushort* Qb    = (ushort*)alloc((size_t)NPAD * 512 * 2);
  ushort* skipb = (ushort*)alloc((size_t)N_NODES * 512 * 2);
  ushort* hb    = (ushort*)alloc((size_t)N_NODES * 512 * 2);
  ushort* Bt1   = (ushort*)alloc((size_t)1024 * 512 * 2);
  ushort* Bt2   = (ushort*)alloc((size_t)1024 * 512 * 2);
  ushort* Bt3   = (ushort*)alloc((size_t)512 * 512 * 2);
  float*  a_sp  = (float*)alloc((size_t)N_NODES * 6 * 2 * 4);
  float*  a_dp  = (float*)alloc((size_t)N_NODES * 6 * 2 * 4);
  int*    cnt   = (int*)alloc((size_t)N_NODES * 4);
  int*    slots = (int*)alloc((size_t)N_NODES * CAP * 4);

  // ---- CSR slots ----
  hipMemsetAsync(cnt, 0, N_NODES * sizeof(int), stream);
  fill_csr_kernel<<<(E_TOT + 255) / 256, 256, 0, stream>>>(ei, cnt, slots);

  // ---- conversions / weight transposes ----
  // (Pb/Qb pad rows need no init: pad rows only affect C rows >= N_NODES,
  //  which the GEMM epilogue skips.)
  convert_x_kernel<<<((NPAD * 512 / 4) + 255) / 256, 256, 0, stream>>>(x, xb);
  transpose_all_kernel<<<dim3(16, 16, 6), dim3(32, 8), 0, stream>>>(
      W1, lW1, W2, lW2, W3, lW3, Bt1, Bt2, Bt3);

  const int NBY = NPAD / 128;          // 157 row tiles
  const int NWG12 = NBY * 8;           // 1256 tiles (8 col tiles of 128)
  const int NWG3  = NBY * 4;           // 628 tiles  (4 col tiles of 128)
  const int PERSIST = 256 * 3;         // 3 blocks/CU co-resident
  const int G12 = NWG12 < PERSIST ? NWG12 : PERSIST;  // 768
  const int G3  = NWG3  < PERSIST ? NWG3  : PERSIST;  // 628

  // ---- layer 1 ----
  mfma_gemm_kernel<ushort><<<G12, 256, 0, stream>>>(
      xb, Bt1, hb, 512, 512, skipb, 512, 512, lb1, as1, ad1, a_sp, a_dp, 4, 128,
      8, NWG12);
  gather12_fused<4, 128><<<N_NODES, 128, 0, stream>>>(cnt, slots, a_sp, a_dp, hb, b1, skipb, Pb);

  // ---- layer 2 ----
  mfma_gemm_kernel<ushort><<<G12, 256, 0, stream>>>(
      Pb, Bt2, hb, 512, 512, skipb, 512, 512, lb2, as2, ad2, a_sp, a_dp, 4, 128,
      8, NWG12);
  gather12_fused<4, 128><<<N_NODES, 128, 0, stream>>>(cnt, slots, a_sp, a_dp, hb, b2, skipb, Qb);

  // ---- layer 3 ----
  mfma_gemm_kernel<float><<<G3, 256, 0, stream>>>(
      Qb, Bt3, hb, 384, 384, out, 64, 64, lb3, as3, ad3, a_sp, a_dp, 6, 64,
      4, NWG3);
  gather3_fused<<<N_NODES, 128, 0, stream>>>(cnt, slots, a_sp, a_dp, hb, b3, out);
}